// Round 5
// baseline (382.074 us; speedup 1.0000x reference)
//
#include <hip/hip_runtime.h>

#define BS 65536
#define DIM 64
#define SD 1024
#define TM 32
#define NTHREADS 512
#define NBLK 512
#define NCHUNK 4
#define TILE 128
#define NTILES 8
#define SROWB 2064        // bytes per S row: 1024 f16 + 16B pad
#define CGS 9.2854e-11f   // exp(-23.1); arbitrary scale, cancels in normalization

// LDS layout (bytes)
#define L_S      0         // [32] rows x 2064B: f16 scores -> f16 e -> bf16 ey (all in-place)
#define L_C2S    66048     // [1024] f32
#define L_Z2S    70144     // [32] f32
#define L_ZYS    70272     // [32] f32
#define L_RMXP   70400     // [4][32] f32 per-cgrp row-max partials
#define L_WRED   70912     // [16] f32
#define LDS_BYTES 70976

// workspace layout (bytes)
#define WS_CBP   0          // 8 tiles x [128 rows x 144B: 64 bf16 + pad]
#define WS_CBT   147456     // 8 tiles x [64 rows(d) x 272B: 128 bf16 + pad]
#define WS_C2    286720     // [1024] f32
#define WS_AVG   290816     // [1024] f32 accumulator (zeroed by prep)
#define WS_APART 294912     // [512][1024] f32 per-block avg partials
#define WS_LPART 2392064    // [512] f32 per-block loss partials

typedef __attribute__((ext_vector_type(8))) short bf16x8;
typedef __attribute__((ext_vector_type(4))) float f32x4;
typedef __attribute__((ext_vector_type(4))) _Float16 f16x4;

__device__ __forceinline__ unsigned short f2bf(float f) {
  union { float f; unsigned int u; } v; v.f = f;
  unsigned int r = v.u + 0x7fffu + ((v.u >> 16) & 1u);
  return (unsigned short)(r >> 16);
}
__device__ __forceinline__ float wsum64(float v) {
  #pragma unroll
  for (int m = 1; m < 64; m <<= 1) v += __shfl_xor(v, m);
  return v;
}
__device__ __forceinline__ bf16x8 pack8(float4 a, float4 b) {
  bf16x8 r;
  r[0]=(short)f2bf(a.x); r[1]=(short)f2bf(a.y); r[2]=(short)f2bf(a.z); r[3]=(short)f2bf(a.w);
  r[4]=(short)f2bf(b.x); r[5]=(short)f2bf(b.y); r[6]=(short)f2bf(b.z); r[7]=(short)f2bf(b.w);
  return r;
}
// LDS-visibility barrier: does NOT drain vmcnt -> global loads stay in flight
__device__ __forceinline__ void bar() {
  asm volatile("s_waitcnt lgkmcnt(0)" ::: "memory");
  __builtin_amdgcn_s_barrier();
  asm volatile("" ::: "memory");
}

// ---------------- prep: padded bf16 codebook tiles (+transposed), c2, zero avgg ----------------
__global__ __launch_bounds__(256) void gvq_prep(const float* __restrict__ cb, char* __restrict__ ws) {
  int gid = blockIdx.x * 256 + threadIdx.x;   // 0..16383
  int j = gid >> 4, dg = gid & 15;
  float4 v = *(const float4*)(cb + j * DIM + dg * 4);
  float s = v.x*v.x + v.y*v.y + v.z*v.z + v.w*v.w;
  s += __shfl_xor(s, 1); s += __shfl_xor(s, 2); s += __shfl_xor(s, 4); s += __shfl_xor(s, 8);
  int tt = j >> 7, jl = j & 127;
  unsigned short b0 = f2bf(v.x), b1 = f2bf(v.y), b2 = f2bf(v.z), b3 = f2bf(v.w);
  uint2 pk;
  pk.x = (unsigned)b0 | ((unsigned)b1 << 16);
  pk.y = (unsigned)b2 | ((unsigned)b3 << 16);
  *(uint2*)(ws + WS_CBP + tt * 18432 + jl * 144 + dg * 8) = pk;
  unsigned short* tb = (unsigned short*)(ws + WS_CBT + tt * 17408 + jl * 2);
  int d = dg * 4;            // 272B rows = 136 u16 stride
  tb[(d + 0) * 136] = b0; tb[(d + 1) * 136] = b1;
  tb[(d + 2) * 136] = b2; tb[(d + 3) * 136] = b3;
  if (dg == 0) ((float*)(ws + WS_C2))[j] = s;
  if (gid < SD) ((float*)(ws + WS_AVG))[gid] = 0.f;
}

// ---------------- main fused kernel: 512 blocks x 4 chunks, 2 blocks/CU pinned ----------------
__global__ __attribute__((amdgpu_flat_work_group_size(NTHREADS, NTHREADS),
                          amdgpu_waves_per_eu(4, 4)))
void gvq_main(
    const float* __restrict__ z, const float* __restrict__ pq,
    const float* __restrict__ u, char* __restrict__ ws,
    float* __restrict__ out)
{
  extern __shared__ char smem[];
  char*  Sb   = smem + L_S;
  float* c2s  = (float*)(smem + L_C2S);
  float* z2s  = (float*)(smem + L_Z2S);
  float* zys  = (float*)(smem + L_ZYS);
  float* rmxp = (float*)(smem + L_RMXP);
  float* wred = (float*)(smem + L_WRED);

  const int t    = threadIdx.x;
  const int lane = t & 63;
  const int wave = t >> 6;
  const int l15  = lane & 15;
  const int lg   = lane >> 4;
  const int rb   = wave & 1;   // 16-row half
  const int cgrp = wave >> 1;  // PA 32-col group / PD 16-dim group
  const int lr0  = wave * 4;   // PB row base

  const char* cbbp = ws + WS_CBP;
  const char* cbtp = ws + WS_CBT;
  const float* c2g = (const float*)(ws + WS_C2);
  float* apart     = (float*)(ws + WS_APART);
  float* lpart     = (float*)(ws + WS_LPART);

  const float weight = 0.5f / fmaxf(pq[0], 1e-10f);

  c2s[t] = c2g[t]; c2s[t + 512] = c2g[t + 512];

  float pav[16];
  #pragma unroll
  for (int i = 0; i < 16; ++i) pav[i] = 0.f;
  float kd_acc = 0.f, kc_acc = 0.f;

  const int paOff = (cgrp * 32 + l15) * 144 + lg * 16;   // + tt*18432 + cbk*2304 + half*64
  const int pdOff = (cgrp * 16 + l15) * 272 + lg * 16;   // + tt*17408 + kb*64

  // prefetch u row0 of chunk 0
  float4 ua0, ua1, ua2, ua3;
  {
    const float* ur = u + (size_t)(blockIdx.x * NCHUNK * TM + lr0) * SD + 4 * lane;
    ua0 = *(const float4*)(ur);
    ua1 = *(const float4*)(ur + 256);
    ua2 = *(const float4*)(ur + 512);
    ua3 = *(const float4*)(ur + 768);
  }

  for (int c = 0; c < NCHUNK; ++c) {
    const int r0 = (blockIdx.x * NCHUNK + c) * TM;

    // ---- P0: z A-frags direct from global, z2 ----
    const int arow = r0 + rb * 16 + l15;
    float4 za = *(const float4*)(z + (size_t)arow * DIM + lg * 8);
    float4 zb = *(const float4*)(z + (size_t)arow * DIM + lg * 8 + 4);
    float4 zc = *(const float4*)(z + (size_t)arow * DIM + 32 + lg * 8);
    float4 zd = *(const float4*)(z + (size_t)arow * DIM + 32 + lg * 8 + 4);
    bf16x8 a0 = pack8(za, zb);
    bf16x8 a1 = pack8(zc, zd);
    float zsq = za.x*za.x+za.y*za.y+za.z*za.z+za.w*za.w
              + zb.x*zb.x+zb.y*zb.y+zb.z*zb.z+zb.w*zb.w
              + zc.x*zc.x+zc.y*zc.y+zc.z*zc.z+zc.w*zc.w
              + zd.x*zd.x+zd.y*zd.y+zd.z*zd.z+zd.w*zd.w;
    zsq += __shfl_xor(zsq, 16); zsq += __shfl_xor(zsq, 32);
    if (lg == 0) z2s[rb * 16 + l15] = zsq;
    bar();  // prev chunk's S reads done; z2s visible

    // ---- PA: S(f16) = -w*(z2 + c2 - 2*z.c), B-frags direct from L2-hot ws ----
    float rmax[4] = {-1e30f, -1e30f, -1e30f, -1e30f};
    for (int tt = 0; tt < NTILES; ++tt) {
      const char* tb = cbbp + tt * 18432 + paOff;
      bf16x8 c00 = *(const bf16x8*)(tb);
      bf16x8 c01 = *(const bf16x8*)(tb + 64);
      bf16x8 c10 = *(const bf16x8*)(tb + 2304);
      bf16x8 c11 = *(const bf16x8*)(tb + 2304 + 64);
      #pragma unroll
      for (int cbk = 0; cbk < 2; ++cbk) {
        f32x4 acc = {0.f, 0.f, 0.f, 0.f};
        acc = __builtin_amdgcn_mfma_f32_16x16x32_bf16(a0, cbk ? c10 : c00, acc, 0, 0, 0);
        acc = __builtin_amdgcn_mfma_f32_16x16x32_bf16(a1, cbk ? c11 : c01, acc, 0, 0, 0);
        int jg = tt * TILE + cgrp * 32 + cbk * 16 + l15;
        float c2v = c2s[jg];
        int rl = rb * 16 + lg * 4;
        #pragma unroll
        for (int rr = 0; rr < 4; ++rr) {
          float logit = -weight * (z2s[rl + rr] + c2v - 2.f * acc[rr]);
          *(_Float16*)(Sb + (rl + rr) * SROWB + jg * 2) = (_Float16)logit;
          rmax[rr] = fmaxf(rmax[rr], logit);
        }
      }
    }
    #pragma unroll
    for (int rr = 0; rr < 4; ++rr) {
      float v = rmax[rr];
      v = fmaxf(v, __shfl_xor(v, 1)); v = fmaxf(v, __shfl_xor(v, 2));
      v = fmaxf(v, __shfl_xor(v, 4)); v = fmaxf(v, __shfl_xor(v, 8));
      if (l15 == 0) rmxp[cgrp * 32 + rb * 16 + lg * 4 + rr] = v;
    }
    bar();  // S + rmxp visible

    // ---- PB: two sweeps, all in-place in the S row ----
    #pragma unroll
    for (int rr = 0; rr < 4; ++rr) {
      const int lr = lr0 + rr;
      char* Srow = Sb + lr * SROWB;
      float4 uc0 = ua0, uc1 = ua1, uc2 = ua2, uc3 = ua3;
      if (rr < 3) {
        const float* un = u + (size_t)(r0 + lr + 1) * SD + 4 * lane;
        ua0 = *(const float4*)(un);
        ua1 = *(const float4*)(un + 256);
        ua2 = *(const float4*)(un + 512);
        ua3 = *(const float4*)(un + 768);
      } else if (c + 1 < NCHUNK) {
        const float* un = u + (size_t)(r0 + TM + lr0) * SD + 4 * lane;
        ua0 = *(const float4*)(un);
        ua1 = *(const float4*)(un + 256);
        ua2 = *(const float4*)(un + 512);
        ua3 = *(const float4*)(un + 768);
      }
      const float m = fmaxf(fmaxf(rmxp[0 * 32 + lr], rmxp[1 * 32 + lr]),
                            fmaxf(rmxp[2 * 32 + lr], rmxp[3 * 32 + lr]));
      // sweep 1: s -> e (f16, in place), Zs, E1
      float Zs = 0.f, E1 = 0.f;
      #pragma unroll
      for (int K = 0; K < 4; ++K) {
        f16x4 s4 = *(const f16x4*)(Srow + K * 512 + 8 * lane);
        float d0 = (float)s4[0] - m, d1 = (float)s4[1] - m;
        float d2 = (float)s4[2] - m, d3 = (float)s4[3] - m;
        float e0 = __expf(d0), e1 = __expf(d1), e2 = __expf(d2), e3 = __expf(d3);
        Zs += (e0 + e1) + (e2 + e3);
        E1 += (e0 * d0 + e1 * d1) + (e2 * d2 + e3 * d3);
        f16x4 e4;
        e4[0] = (_Float16)e0; e4[1] = (_Float16)e1;
        e4[2] = (_Float16)e2; e4[3] = (_Float16)e3;
        *(f16x4*)(Srow + K * 512 + 8 * lane) = e4;
      }
      #pragma unroll
      for (int mk = 1; mk < 64; mk <<= 1) {
        Zs += __shfl_xor(Zs, mk);
        E1 += __shfl_xor(E1, mk);
      }
      float invZ = 1.f / Zs;
      kd_acc += E1 * invZ - __logf(Zs);
      // sweep 2: e -> ey (bf16, in place), pav, Zy
      float Zy = 0.f;
      #pragma unroll
      for (int K = 0; K < 4; ++K) {
        f16x4 e4 = *(const f16x4*)(Srow + K * 512 + 8 * lane);
        float e0 = (float)e4[0], e1 = (float)e4[1];
        float e2 = (float)e4[2], e3 = (float)e4[3];
        pav[K*4+0] += e0 * invZ; pav[K*4+1] += e1 * invZ;
        pav[K*4+2] += e2 * invZ; pav[K*4+3] += e3 * invZ;
        float4 uc = (K == 0) ? uc0 : (K == 1) ? uc1 : (K == 2) ? uc2 : uc3;
        float L0 = 1e-10f - __logf(uc.x + 1e-10f);
        float L1 = 1e-10f - __logf(uc.y + 1e-10f);
        float L2 = 1e-10f - __logf(uc.z + 1e-10f);
        float L3 = 1e-10f - __logf(uc.w + 1e-10f);
        float y0 = e0 * (CGS * __builtin_amdgcn_rcpf(L0));
        float y1 = e1 * (CGS * __builtin_amdgcn_rcpf(L1));
        float y2 = e2 * (CGS * __builtin_amdgcn_rcpf(L2));
        float y3 = e3 * (CGS * __builtin_amdgcn_rcpf(L3));
        Zy += (y0 + y1) + (y2 + y3);
        uint2 pk;
        pk.x = (unsigned)f2bf(y0) | ((unsigned)f2bf(y1) << 16);
        pk.y = (unsigned)f2bf(y2) | ((unsigned)f2bf(y3) << 16);
        *(uint2*)(Srow + K * 512 + 8 * lane) = pk;
      }
      Zy = wsum64(Zy);
      if (lane == 0) zys[lr] = Zy;
    }
    bar();  // ey + zys visible

    // ---- PD: z_q = Ey @ codebook, B-frags direct from L2-hot ws ----
    f32x4 dacc = {0.f, 0.f, 0.f, 0.f};
    for (int tt = 0; tt < NTILES; ++tt) {
      const char* tb = cbtp + tt * 17408 + pdOff;
      bf16x8 d0 = *(const bf16x8*)(tb);
      bf16x8 d1 = *(const bf16x8*)(tb + 64);
      bf16x8 d2 = *(const bf16x8*)(tb + 128);
      bf16x8 d3 = *(const bf16x8*)(tb + 192);
      const char* arow_p = Sb + (rb * 16 + l15) * SROWB + (tt * 128 + lg * 8) * 2;
      bf16x8 pa0 = *(const bf16x8*)(arow_p);
      bf16x8 pa1 = *(const bf16x8*)(arow_p + 64);
      bf16x8 pa2 = *(const bf16x8*)(arow_p + 128);
      bf16x8 pa3 = *(const bf16x8*)(arow_p + 192);
      dacc = __builtin_amdgcn_mfma_f32_16x16x32_bf16(pa0, d0, dacc, 0, 0, 0);
      dacc = __builtin_amdgcn_mfma_f32_16x16x32_bf16(pa1, d1, dacc, 0, 0, 0);
      dacc = __builtin_amdgcn_mfma_f32_16x16x32_bf16(pa2, d2, dacc, 0, 0, 0);
      dacc = __builtin_amdgcn_mfma_f32_16x16x32_bf16(pa3, d3, dacc, 0, 0, 0);
    }

    // ---- PE: normalize from regs, write out, kc per-lane ----
    {
      int col = cgrp * 16 + l15;
      int rlb = r0 + rb * 16 + lg * 4;
      #pragma unroll
      for (int rr = 0; rr < 4; ++rr) {
        float v = dacc[rr] / zys[rb * 16 + lg * 4 + rr];
        out[(size_t)(rlb + rr) * DIM + col] = v;
        float zvv = z[(size_t)(rlb + rr) * DIM + col];
        float dq = zvv - v;
        kc_acc += dq * dq;
      }
    }
  }

  // ---- flush: per-block partials (no global atomics) ----
  bar();
  float* pavb = (float*)smem;  // reuse S region: [8][1024] f32
  #pragma unroll
  for (int k = 0; k < 4; ++k) {
    float4 v4 = {pav[4*k+0], pav[4*k+1], pav[4*k+2], pav[4*k+3]};
    *(float4*)(pavb + wave * 1024 + k * 256 + 4 * lane) = v4;
  }
  float kcs = wsum64(kc_acc);
  if (lane == 0) wred[wave] = kd_acc + kcs * weight;
  bar();
  {
    int c0 = t, c1 = t + 512;
    float s0 = 0.f, s1 = 0.f;
    #pragma unroll
    for (int w = 0; w < 8; ++w) { s0 += pavb[w * 1024 + c0]; s1 += pavb[w * 1024 + c1]; }
    apart[(size_t)blockIdx.x * 1024 + c0] = s0;
    apart[(size_t)blockIdx.x * 1024 + c1] = s1;
    if (t == 0) {
      float L = 0.f;
      #pragma unroll
      for (int w = 0; w < 8; ++w) L += wred[w];
      lpart[blockIdx.x] = L;
    }
  }
}

// ---------------- reduce avg partials: 32 blocks x 16 rows each ----------------
__global__ __launch_bounds__(512) void gvq_red(char* __restrict__ ws) {
  const float* apart = (const float*)(ws + WS_APART);
  float* avgg        = (float*)(ws + WS_AVG);
  int bb = blockIdx.x, t = threadIdx.x;
  float s0 = 0.f, s1 = 0.f;
  #pragma unroll
  for (int r = 0; r < 16; ++r) {
    float2 v = *(const float2*)(apart + (size_t)(bb * 16 + r) * 1024 + t * 2);
    s0 += v.x; s1 += v.y;
  }
  atomicAdd(&avgg[t * 2], s0);
  atomicAdd(&avgg[t * 2 + 1], s1);
}

// ---------------- final: loss + perplexity ----------------
__global__ __launch_bounds__(256) void gvq_final(const char* __restrict__ ws, float* __restrict__ out) {
  const float* avgg  = (const float*)(ws + WS_AVG);
  const float* lpart = (const float*)(ws + WS_LPART);
  int t = threadIdx.x;
  float s = 0.f;
  #pragma unroll
  for (int i = t; i < SD; i += 256) {
    float a = avgg[i] * (1.f / 65536.f);
    s += a * logf(a + 1e-7f);
  }
  float lp = lpart[t] + lpart[t + 256];
  s = wsum64(s); lp = wsum64(lp);
  __shared__ float ws1[4], ws2[4];
  if ((t & 63) == 0) { ws1[t >> 6] = s; ws2[t >> 6] = lp; }
  __syncthreads();
  if (t == 0) {
    float tot = ws1[0] + ws1[1] + ws1[2] + ws1[3];
    float L   = ws2[0] + ws2[1] + ws2[2] + ws2[3];
    out[(size_t)BS * DIM]     = L * (1.f / 65536.f);
    out[(size_t)BS * DIM + 1] = expf(-tot);
  }
}

extern "C" void kernel_launch(void* const* d_in, const int* in_sizes, int n_in,
                              void* d_out, int out_size, void* d_ws, size_t ws_size,
                              hipStream_t stream) {
  (void)in_sizes; (void)n_in; (void)out_size; (void)ws_size;
  const float* z  = (const float*)d_in[0];
  const float* pq = (const float*)d_in[1];
  const float* cb = (const float*)d_in[2];
  const float* u  = (const float*)d_in[3];
  char* ws   = (char*)d_ws;
  float* out = (float*)d_out;
  hipFuncSetAttribute((const void*)gvq_main, hipFuncAttributeMaxDynamicSharedMemorySize, LDS_BYTES);
  gvq_prep<<<64, 256, 0, stream>>>(cb, ws);
  gvq_main<<<NBLK, NTHREADS, LDS_BYTES, stream>>>(z, pq, u, ws, out);
  gvq_red<<<32, 512, 0, stream>>>(ws);
  gvq_final<<<1, 256, 0, stream>>>(ws, out);
}

// Round 6
// 271.921 us; speedup vs baseline: 1.4051x; 1.4051x over previous
//
#include <hip/hip_runtime.h>

#define BS 65536
#define DIM 64
#define SD 1024
#define TM 32
#define NTHREADS 512
#define NBLK 512
#define NCHUNK 4
#define TILE 128
#define NTILES 8
#define SROWB 2064        // bytes per S row: 1024 f16 + 16B pad
#define CGS 9.2854e-11f   // exp(-23.1); arbitrary scale, cancels in normalization

// LDS layout (bytes)
#define L_S      0         // [32] rows x 2064B: f16 scores -> f16 e -> bf16 ey (all in-place)
#define L_C2S    66048     // [1024] f32
#define L_Z2S    70144     // [32] f32
#define L_ZYS    70272     // [32] f32
#define L_RMXP   70400     // [4][32] f32 per-cgrp row-max partials
#define L_WRED   70912     // [16] f32
#define LDS_BYTES 70976

// workspace layout (bytes)
#define WS_CBP   0          // 8 tiles x [128 rows x 144B: 64 bf16 + pad]
#define WS_CBT   147456     // 8 tiles x [64 rows(d) x 272B: 128 bf16 + pad]
#define WS_C2    286720     // [1024] f32
#define WS_AVG   290816     // [1024] f32 accumulator (zeroed by prep)
#define WS_APART 294912     // [512][1024] f32 per-block avg partials
#define WS_LPART 2392064    // [512] f32 per-block loss partials

typedef __attribute__((ext_vector_type(8))) short bf16x8;
typedef __attribute__((ext_vector_type(4))) float f32x4;
typedef __attribute__((ext_vector_type(4))) _Float16 f16x4;

__device__ __forceinline__ unsigned short f2bf(float f) {
  union { float f; unsigned int u; } v; v.f = f;
  unsigned int r = v.u + 0x7fffu + ((v.u >> 16) & 1u);
  return (unsigned short)(r >> 16);
}
__device__ __forceinline__ float wsum64(float v) {
  #pragma unroll
  for (int m = 1; m < 64; m <<= 1) v += __shfl_xor(v, m);
  return v;
}
__device__ __forceinline__ bf16x8 pack8(float4 a, float4 b) {
  bf16x8 r;
  r[0]=(short)f2bf(a.x); r[1]=(short)f2bf(a.y); r[2]=(short)f2bf(a.z); r[3]=(short)f2bf(a.w);
  r[4]=(short)f2bf(b.x); r[5]=(short)f2bf(b.y); r[6]=(short)f2bf(b.z); r[7]=(short)f2bf(b.w);
  return r;
}
// LDS-visibility barrier: does NOT drain vmcnt -> global loads stay in flight
__device__ __forceinline__ void bar() {
  asm volatile("s_waitcnt lgkmcnt(0)" ::: "memory");
  __builtin_amdgcn_s_barrier();
  asm volatile("" ::: "memory");
}

// ---------------- prep: padded bf16 codebook tiles (+transposed), c2, zero avgg ----------------
__global__ __launch_bounds__(256) void gvq_prep(const float* __restrict__ cb, char* __restrict__ ws) {
  int gid = blockIdx.x * 256 + threadIdx.x;   // 0..16383
  int j = gid >> 4, dg = gid & 15;
  float4 v = *(const float4*)(cb + j * DIM + dg * 4);
  float s = v.x*v.x + v.y*v.y + v.z*v.z + v.w*v.w;
  s += __shfl_xor(s, 1); s += __shfl_xor(s, 2); s += __shfl_xor(s, 4); s += __shfl_xor(s, 8);
  int tt = j >> 7, jl = j & 127;
  unsigned short b0 = f2bf(v.x), b1 = f2bf(v.y), b2 = f2bf(v.z), b3 = f2bf(v.w);
  uint2 pk;
  pk.x = (unsigned)b0 | ((unsigned)b1 << 16);
  pk.y = (unsigned)b2 | ((unsigned)b3 << 16);
  *(uint2*)(ws + WS_CBP + tt * 18432 + jl * 144 + dg * 8) = pk;
  unsigned short* tb = (unsigned short*)(ws + WS_CBT + tt * 17408 + jl * 2);
  int d = dg * 4;            // 272B rows = 136 u16 stride
  tb[(d + 0) * 136] = b0; tb[(d + 1) * 136] = b1;
  tb[(d + 2) * 136] = b2; tb[(d + 3) * 136] = b3;
  if (dg == 0) ((float*)(ws + WS_C2))[j] = s;
  if (gid < SD) ((float*)(ws + WS_AVG))[gid] = 0.f;
}

// ---------------- main fused kernel: 512 blocks x 4 chunks, 2 blocks/CU ----------------
__global__ __launch_bounds__(NTHREADS, 2) void gvq_main(
    const float* __restrict__ z, const float* __restrict__ pq,
    const float* __restrict__ u, char* __restrict__ ws,
    float* __restrict__ out)
{
  extern __shared__ char smem[];
  char*  Sb   = smem + L_S;
  float* c2s  = (float*)(smem + L_C2S);
  float* z2s  = (float*)(smem + L_Z2S);
  float* zys  = (float*)(smem + L_ZYS);
  float* rmxp = (float*)(smem + L_RMXP);
  float* wred = (float*)(smem + L_WRED);

  const int t    = threadIdx.x;
  const int lane = t & 63;
  const int wave = t >> 6;
  const int l15  = lane & 15;
  const int lg   = lane >> 4;
  const int rb   = wave & 1;   // 16-row half
  const int cgrp = wave >> 1;  // PA 32-col group / PD 16-dim group
  const int lr0  = wave * 4;   // PB row base

  const char* cbbp = ws + WS_CBP;
  const char* cbtp = ws + WS_CBT;
  const float* c2g = (const float*)(ws + WS_C2);
  float* apart     = (float*)(ws + WS_APART);
  float* lpart     = (float*)(ws + WS_LPART);

  const float weight = 0.5f / fmaxf(pq[0], 1e-10f);

  c2s[t] = c2g[t]; c2s[t + 512] = c2g[t + 512];

  float pav[16];
  #pragma unroll
  for (int i = 0; i < 16; ++i) pav[i] = 0.f;
  float kd_acc = 0.f, kc_acc = 0.f;

  const int paOff = (cgrp * 32 + l15) * 144 + lg * 16;   // + tt*18432 + cbk*2304 + half*64
  const int pdOff = (cgrp * 16 + l15) * 272 + lg * 16;   // + tt*17408 + kb*64

  // prefetch u row0 of chunk 0 (one row resident at a time)
  float4 ua0, ua1, ua2, ua3;
  {
    const float* ur = u + (size_t)(blockIdx.x * NCHUNK * TM + lr0) * SD + 4 * lane;
    ua0 = *(const float4*)(ur);
    ua1 = *(const float4*)(ur + 256);
    ua2 = *(const float4*)(ur + 512);
    ua3 = *(const float4*)(ur + 768);
  }

  for (int c = 0; c < NCHUNK; ++c) {
    const int r0 = (blockIdx.x * NCHUNK + c) * TM;

    // ---- P0: z A-frags direct from global, z2 ----
    const int arow = r0 + rb * 16 + l15;
    float4 za = *(const float4*)(z + (size_t)arow * DIM + lg * 8);
    float4 zb = *(const float4*)(z + (size_t)arow * DIM + lg * 8 + 4);
    float4 zc = *(const float4*)(z + (size_t)arow * DIM + 32 + lg * 8);
    float4 zd = *(const float4*)(z + (size_t)arow * DIM + 32 + lg * 8 + 4);
    bf16x8 a0 = pack8(za, zb);
    bf16x8 a1 = pack8(zc, zd);
    float zsq = za.x*za.x+za.y*za.y+za.z*za.z+za.w*za.w
              + zb.x*zb.x+zb.y*zb.y+zb.z*zb.z+zb.w*zb.w
              + zc.x*zc.x+zc.y*zc.y+zc.z*zc.z+zc.w*zc.w
              + zd.x*zd.x+zd.y*zd.y+zd.z*zd.z+zd.w*zd.w;
    zsq += __shfl_xor(zsq, 16); zsq += __shfl_xor(zsq, 32);
    if (lg == 0) z2s[rb * 16 + l15] = zsq;
    bar();  // prev chunk's S reads done; z2s visible

    // ---- PA: S(f16) = -w*(z2 + c2 - 2*z.c), B-frags direct from L2-hot ws ----
    float rmax[4] = {-1e30f, -1e30f, -1e30f, -1e30f};
    for (int tt = 0; tt < NTILES; ++tt) {
      const char* tb = cbbp + tt * 18432 + paOff;
      bf16x8 c00 = *(const bf16x8*)(tb);
      bf16x8 c01 = *(const bf16x8*)(tb + 64);
      bf16x8 c10 = *(const bf16x8*)(tb + 2304);
      bf16x8 c11 = *(const bf16x8*)(tb + 2304 + 64);
      #pragma unroll
      for (int cbk = 0; cbk < 2; ++cbk) {
        f32x4 acc = {0.f, 0.f, 0.f, 0.f};
        acc = __builtin_amdgcn_mfma_f32_16x16x32_bf16(a0, cbk ? c10 : c00, acc, 0, 0, 0);
        acc = __builtin_amdgcn_mfma_f32_16x16x32_bf16(a1, cbk ? c11 : c01, acc, 0, 0, 0);
        int jg = tt * TILE + cgrp * 32 + cbk * 16 + l15;
        float c2v = c2s[jg];
        int rl = rb * 16 + lg * 4;
        #pragma unroll
        for (int rr = 0; rr < 4; ++rr) {
          float logit = -weight * (z2s[rl + rr] + c2v - 2.f * acc[rr]);
          *(_Float16*)(Sb + (rl + rr) * SROWB + jg * 2) = (_Float16)logit;
          rmax[rr] = fmaxf(rmax[rr], logit);
        }
      }
    }
    #pragma unroll
    for (int rr = 0; rr < 4; ++rr) {
      float v = rmax[rr];
      v = fmaxf(v, __shfl_xor(v, 1)); v = fmaxf(v, __shfl_xor(v, 2));
      v = fmaxf(v, __shfl_xor(v, 4)); v = fmaxf(v, __shfl_xor(v, 8));
      if (l15 == 0) rmxp[cgrp * 32 + rb * 16 + lg * 4 + rr] = v;
    }
    bar();  // S + rmxp visible

    // ---- PB: two in-place sweeps; u consumed directly from ua, refilled after use ----
    #pragma unroll
    for (int rr = 0; rr < 4; ++rr) {
      const int lr = lr0 + rr;
      char* Srow = Sb + lr * SROWB;
      const float m = fmaxf(fmaxf(rmxp[0 * 32 + lr], rmxp[1 * 32 + lr]),
                            fmaxf(rmxp[2 * 32 + lr], rmxp[3 * 32 + lr]));
      // sweep 1: s -> e (f16, in place), Zs, E1
      float Zs = 0.f, E1 = 0.f;
      #pragma unroll
      for (int K = 0; K < 4; ++K) {
        f16x4 s4 = *(const f16x4*)(Srow + K * 512 + 8 * lane);
        float d0 = (float)s4[0] - m, d1 = (float)s4[1] - m;
        float d2 = (float)s4[2] - m, d3 = (float)s4[3] - m;
        float e0 = __expf(d0), e1 = __expf(d1), e2 = __expf(d2), e3 = __expf(d3);
        Zs += (e0 + e1) + (e2 + e3);
        E1 += (e0 * d0 + e1 * d1) + (e2 * d2 + e3 * d3);
        f16x4 e4;
        e4[0] = (_Float16)e0; e4[1] = (_Float16)e1;
        e4[2] = (_Float16)e2; e4[3] = (_Float16)e3;
        *(f16x4*)(Srow + K * 512 + 8 * lane) = e4;
      }
      #pragma unroll
      for (int mk = 1; mk < 64; mk <<= 1) {
        Zs += __shfl_xor(Zs, mk);
        E1 += __shfl_xor(E1, mk);
      }
      float invZ = 1.f / Zs;
      kd_acc += E1 * invZ - __logf(Zs);
      // sweep 2: e -> ey (bf16, in place), pav, Zy; consumes ua0..ua3
      float Zy = 0.f;
      #pragma unroll
      for (int K = 0; K < 4; ++K) {
        f16x4 e4 = *(const f16x4*)(Srow + K * 512 + 8 * lane);
        float e0 = (float)e4[0], e1 = (float)e4[1];
        float e2 = (float)e4[2], e3 = (float)e4[3];
        pav[K*4+0] += e0 * invZ; pav[K*4+1] += e1 * invZ;
        pav[K*4+2] += e2 * invZ; pav[K*4+3] += e3 * invZ;
        float4 uc = (K == 0) ? ua0 : (K == 1) ? ua1 : (K == 2) ? ua2 : ua3;
        float L0 = 1e-10f - __logf(uc.x + 1e-10f);
        float L1 = 1e-10f - __logf(uc.y + 1e-10f);
        float L2 = 1e-10f - __logf(uc.z + 1e-10f);
        float L3 = 1e-10f - __logf(uc.w + 1e-10f);
        float y0 = e0 * (CGS * __builtin_amdgcn_rcpf(L0));
        float y1 = e1 * (CGS * __builtin_amdgcn_rcpf(L1));
        float y2 = e2 * (CGS * __builtin_amdgcn_rcpf(L2));
        float y3 = e3 * (CGS * __builtin_amdgcn_rcpf(L3));
        Zy += (y0 + y1) + (y2 + y3);
        uint2 pk;
        pk.x = (unsigned)f2bf(y0) | ((unsigned)f2bf(y1) << 16);
        pk.y = (unsigned)f2bf(y2) | ((unsigned)f2bf(y3) << 16);
        *(uint2*)(Srow + K * 512 + 8 * lane) = pk;
      }
      // refill ua for the next row AFTER consumption (only one row ever resident)
      if (rr < 3) {
        const float* un = u + (size_t)(r0 + lr + 1) * SD + 4 * lane;
        ua0 = *(const float4*)(un);
        ua1 = *(const float4*)(un + 256);
        ua2 = *(const float4*)(un + 512);
        ua3 = *(const float4*)(un + 768);
      } else if (c + 1 < NCHUNK) {
        const float* un = u + (size_t)(r0 + TM + lr0) * SD + 4 * lane;
        ua0 = *(const float4*)(un);
        ua1 = *(const float4*)(un + 256);
        ua2 = *(const float4*)(un + 512);
        ua3 = *(const float4*)(un + 768);
      }
      Zy = wsum64(Zy);
      if (lane == 0) zys[lr] = Zy;
    }
    bar();  // ey + zys visible

    // ---- PD: z_q = Ey @ codebook, B-frags direct from L2-hot ws ----
    f32x4 dacc = {0.f, 0.f, 0.f, 0.f};
    for (int tt = 0; tt < NTILES; ++tt) {
      const char* tb = cbtp + tt * 17408 + pdOff;
      bf16x8 d0 = *(const bf16x8*)(tb);
      bf16x8 d1 = *(const bf16x8*)(tb + 64);
      bf16x8 d2 = *(const bf16x8*)(tb + 128);
      bf16x8 d3 = *(const bf16x8*)(tb + 192);
      const char* arow_p = Sb + (rb * 16 + l15) * SROWB + (tt * 128 + lg * 8) * 2;
      bf16x8 pa0 = *(const bf16x8*)(arow_p);
      bf16x8 pa1 = *(const bf16x8*)(arow_p + 64);
      bf16x8 pa2 = *(const bf16x8*)(arow_p + 128);
      bf16x8 pa3 = *(const bf16x8*)(arow_p + 192);
      dacc = __builtin_amdgcn_mfma_f32_16x16x32_bf16(pa0, d0, dacc, 0, 0, 0);
      dacc = __builtin_amdgcn_mfma_f32_16x16x32_bf16(pa1, d1, dacc, 0, 0, 0);
      dacc = __builtin_amdgcn_mfma_f32_16x16x32_bf16(pa2, d2, dacc, 0, 0, 0);
      dacc = __builtin_amdgcn_mfma_f32_16x16x32_bf16(pa3, d3, dacc, 0, 0, 0);
    }

    // ---- PE: normalize from regs, write out, kc per-lane ----
    {
      int col = cgrp * 16 + l15;
      int rlb = r0 + rb * 16 + lg * 4;
      #pragma unroll
      for (int rr = 0; rr < 4; ++rr) {
        float v = dacc[rr] / zys[rb * 16 + lg * 4 + rr];
        out[(size_t)(rlb + rr) * DIM + col] = v;
        float zvv = z[(size_t)(rlb + rr) * DIM + col];
        float dq = zvv - v;
        kc_acc += dq * dq;
      }
    }
  }

  // ---- flush: per-block partials (no global atomics) ----
  bar();
  float* pavb = (float*)smem;  // reuse S region: [8][1024] f32
  #pragma unroll
  for (int k = 0; k < 4; ++k) {
    float4 v4 = {pav[4*k+0], pav[4*k+1], pav[4*k+2], pav[4*k+3]};
    *(float4*)(pavb + wave * 1024 + k * 256 + 4 * lane) = v4;
  }
  float kcs = wsum64(kc_acc);
  if (lane == 0) wred[wave] = kd_acc + kcs * weight;
  bar();
  {
    int c0 = t, c1 = t + 512;
    float s0 = 0.f, s1 = 0.f;
    #pragma unroll
    for (int w = 0; w < 8; ++w) { s0 += pavb[w * 1024 + c0]; s1 += pavb[w * 1024 + c1]; }
    apart[(size_t)blockIdx.x * 1024 + c0] = s0;
    apart[(size_t)blockIdx.x * 1024 + c1] = s1;
    if (t == 0) {
      float L = 0.f;
      #pragma unroll
      for (int w = 0; w < 8; ++w) L += wred[w];
      lpart[blockIdx.x] = L;
    }
  }
}

// ---------------- reduce avg partials: 32 blocks x 16 rows each ----------------
__global__ __launch_bounds__(512) void gvq_red(char* __restrict__ ws) {
  const float* apart = (const float*)(ws + WS_APART);
  float* avgg        = (float*)(ws + WS_AVG);
  int bb = blockIdx.x, t = threadIdx.x;
  float s0 = 0.f, s1 = 0.f;
  #pragma unroll
  for (int r = 0; r < 16; ++r) {
    float2 v = *(const float2*)(apart + (size_t)(bb * 16 + r) * 1024 + t * 2);
    s0 += v.x; s1 += v.y;
  }
  atomicAdd(&avgg[t * 2], s0);
  atomicAdd(&avgg[t * 2 + 1], s1);
}

// ---------------- final: loss + perplexity ----------------
__global__ __launch_bounds__(256) void gvq_final(const char* __restrict__ ws, float* __restrict__ out) {
  const float* avgg  = (const float*)(ws + WS_AVG);
  const float* lpart = (const float*)(ws + WS_LPART);
  int t = threadIdx.x;
  float s = 0.f;
  #pragma unroll
  for (int i = t; i < SD; i += 256) {
    float a = avgg[i] * (1.f / 65536.f);
    s += a * logf(a + 1e-7f);
  }
  float lp = lpart[t] + lpart[t + 256];
  s = wsum64(s); lp = wsum64(lp);
  __shared__ float ws1[4], ws2[4];
  if ((t & 63) == 0) { ws1[t >> 6] = s; ws2[t >> 6] = lp; }
  __syncthreads();
  if (t == 0) {
    float tot = ws1[0] + ws1[1] + ws1[2] + ws1[3];
    float L   = ws2[0] + ws2[1] + ws2[2] + ws2[3];
    out[(size_t)BS * DIM]     = L * (1.f / 65536.f);
    out[(size_t)BS * DIM + 1] = expf(-tot);
  }
}

extern "C" void kernel_launch(void* const* d_in, const int* in_sizes, int n_in,
                              void* d_out, int out_size, void* d_ws, size_t ws_size,
                              hipStream_t stream) {
  (void)in_sizes; (void)n_in; (void)out_size; (void)ws_size;
  const float* z  = (const float*)d_in[0];
  const float* pq = (const float*)d_in[1];
  const float* cb = (const float*)d_in[2];
  const float* u  = (const float*)d_in[3];
  char* ws   = (char*)d_ws;
  float* out = (float*)d_out;
  hipFuncSetAttribute((const void*)gvq_main, hipFuncAttributeMaxDynamicSharedMemorySize, LDS_BYTES);
  gvq_prep<<<64, 256, 0, stream>>>(cb, ws);
  gvq_main<<<NBLK, NTHREADS, LDS_BYTES, stream>>>(z, pq, u, ws, out);
  gvq_red<<<32, 512, 0, stream>>>(ws);
  gvq_final<<<1, 256, 0, stream>>>(ws, out);
}